// Round 5
// baseline (1101.764 us; speedup 1.0000x reference)
//
#include <hip/hip_runtime.h>

// 2-layer LSTM encoder, B=128, T=1024, F=1, HID=128, EMB=64.
// R5: WG = 256 thr (4 waves), one batch per WG, ALL waves identical:
//   wave w: L1 tiles {2w+p+8g : p in 0..1, g in 0..3} = 32 MFMA
//           L2 tiles {w+4g}                           = 24 MFMA
// MFMA chains depth 2-3, C chained from a persistent zero reg (no per-step
// AGPR init); bias + x*w added as scalar post-add in the elementwise.
// Superstep s = L1(s) || L2(s-1), ONE 4-wave barrier per superstep.
// Ping-pong H1/H2 (hazard audit unchanged from R4).

#define TB   1024
#define HID1 128
#define EMB2 64

typedef _Float16 f16x8 __attribute__((ext_vector_type(8)));
typedef float    f32x4 __attribute__((ext_vector_type(4)));

#define MFMA16(a,b,c) __builtin_amdgcn_mfma_f32_16x16x32_f16((a),(b),(c),0,0,0)

static __device__ __forceinline__ float fast_exp2(float x){
#if __has_builtin(__builtin_amdgcn_exp2f)
  return __builtin_amdgcn_exp2f(x);
#else
  return __exp2f(x);
#endif
}
static __device__ __forceinline__ float fast_rcp(float x){
#if __has_builtin(__builtin_amdgcn_rcpf)
  return __builtin_amdgcn_rcpf(x);
#else
  return 1.0f / x;
#endif
}
static __device__ __forceinline__ float sigmoid_f(float x){
  return fast_rcp(1.0f + fast_exp2(-1.44269504088896340736f * x));
}
static __device__ __forceinline__ float tanh_f(float x){
  return 1.0f - 2.0f * fast_rcp(1.0f + fast_exp2(2.88539008177792681472f * x));
}

static __device__ __forceinline__ f16x8 load_frag(const float* p){
  f16x8 r;
  #pragma unroll
  for (int j = 0; j < 8; ++j) r[j] = (_Float16)p[j];
  return r;
}

__launch_bounds__(256, 1)
__global__ void lstm2_kernel(const float* __restrict__ x,
                             const float* __restrict__ w_ih1,
                             const float* __restrict__ w_hh1,
                             const float* __restrict__ b_ih1,
                             const float* __restrict__ b_hh1,
                             const float* __restrict__ w_ih2,
                             const float* __restrict__ w_hh2,
                             const float* __restrict__ b_ih2,
                             const float* __restrict__ b_hh2,
                             float* __restrict__ out)
{
  __shared__ __align__(16) float    xs[TB];
  __shared__ __align__(16) _Float16 H1[2][HID1];  // h1 ping-pong
  __shared__ __align__(16) _Float16 H2[2][EMB2];  // h2 ping-pong

  const int t    = threadIdx.x;   // 0..255
  const int b    = blockIdx.x;    // 0..127
  const int l    = t & 63;        // lane
  const int w    = t >> 6;        // wave 0..3
  const int col  = l & 15;
  const int quad = l >> 4;

  // ---- L1 weight B-fragments: tiles T = 2w + p + 8g ----
  f16x8 B1[4][2][4];
  #pragma unroll
  for (int g = 0; g < 4; ++g)
    #pragma unroll
    for (int p = 0; p < 2; ++p){
      const int nA = (2*w + p + 8*g)*16 + col;
      #pragma unroll
      for (int k = 0; k < 4; ++k)
        B1[g][p][k] = load_frag(w_hh1 + nA*HID1 + k*32 + quad*8);
    }

  // ---- L2 weight B-fragments: tiles T2 = w + 4g ----
  f16x8 B2i[4][4], B2h[4][2];
  #pragma unroll
  for (int g = 0; g < 4; ++g){
    const int nB = (w + 4*g)*16 + col;
    #pragma unroll
    for (int k = 0; k < 4; ++k)
      B2i[g][k] = load_frag(w_ih2 + nB*HID1 + k*32 + quad*8);
    #pragma unroll
    for (int k = 0; k < 2; ++k)
      B2h[g][k] = load_frag(w_hh2 + nB*EMB2 + k*32 + quad*8);
  }

  // ---- per-lane elementwise parameters ----
  float bias1g[4], wx1g[4], bias2g[4];
  const int cA = 32*w + l;           // L1 cell (valid l<32)
  const int cB = 16*w + l;           // L2 cell (valid l<16)
  if (l < 32){
    #pragma unroll
    for (int g = 0; g < 4; ++g){
      const int r = g*HID1 + cA;
      bias1g[g] = b_ih1[r] + b_hh1[r];
      wx1g[g]   = w_ih1[r];          // w_ih1 is (512,1)
    }
  }
  if (l < 16){
    #pragma unroll
    for (int g = 0; g < 4; ++g){
      const int r = g*EMB2 + cB;
      bias2g[g] = b_ih2[r] + b_hh2[r];
    }
  }

  // ---- x preload (float4: 256 thr x 16B = 4 KB) + state init ----
  ((float4*)xs)[t] = ((const float4*)(x + b*TB))[t];
  if (t < HID1) { H1[0][t] = (_Float16)0.0f; H1[1][t] = (_Float16)0.0f; }
  else if (t < HID1 + EMB2){
    H2[0][t-HID1] = (_Float16)0.0f; H2[1][t-HID1] = (_Float16)0.0f;
  }
  __syncthreads();

  float c1 = 0.0f, c2 = 0.0f;
  const f32x4 zacc = {0.0f, 0.0f, 0.0f, 0.0f};   // persistent zero C operand

#define LOAD_A1(slot, a)                                        \
  {                                                             \
    const f16x8* p_ = (const f16x8*)&H1[(slot)][0];             \
    _Pragma("unroll")                                           \
    for (int k_ = 0; k_ < 4; ++k_) (a)[k_] = p_[4*k_ + quad];   \
  }

#define PHASE_A(a1, s)                                          \
  {                                                             \
    const float xt_ = xs[(s)];                                  \
    f32x4 aA_[4][2], aB_[4][2];                                 \
    _Pragma("unroll")                                           \
    for (int g_ = 0; g_ < 4; ++g_)                              \
      _Pragma("unroll")                                         \
      for (int p_ = 0; p_ < 2; ++p_){                           \
        aA_[g_][p_] = MFMA16((a1)[0], B1[g_][p_][0], zacc);     \
        aB_[g_][p_] = MFMA16((a1)[2], B1[g_][p_][2], zacc);     \
      }                                                         \
    _Pragma("unroll")                                           \
    for (int g_ = 0; g_ < 4; ++g_)                              \
      _Pragma("unroll")                                         \
      for (int p_ = 0; p_ < 2; ++p_){                           \
        aA_[g_][p_] = MFMA16((a1)[1], B1[g_][p_][1], aA_[g_][p_]); \
        aB_[g_][p_] = MFMA16((a1)[3], B1[g_][p_][3], aB_[g_][p_]); \
      }                                                         \
    if (l < 32){                                                \
      const int psel_ = (l >> 4) & 1;                           \
      float g4_[4];                                             \
      _Pragma("unroll")                                         \
      for (int g_ = 0; g_ < 4; ++g_){                           \
        float v0_ = aA_[g_][0][0] + aB_[g_][0][0];              \
        float v1_ = aA_[g_][1][0] + aB_[g_][1][0];              \
        float pre_ = __builtin_fmaf(xt_, wx1g[g_], bias1g[g_]); \
        g4_[g_] = (psel_ ? v1_ : v0_) + pre_;                   \
      }                                                         \
      c1 = sigmoid_f(g4_[1]) * c1 + sigmoid_f(g4_[0]) * tanh_f(g4_[2]); \
      float h_ = sigmoid_f(g4_[3]) * tanh_f(c1);                \
      H1[(s) & 1][cA] = (_Float16)h_;                           \
    }                                                           \
  }

#define PHASE_B(a1, s2, store_out)                              \
  {                                                             \
    const f16x8* pA2_ = (const f16x8*)&H2[((s2) + 1) & 1][0];   \
    f16x8 a2_[2];                                               \
    _Pragma("unroll")                                           \
    for (int k_ = 0; k_ < 2; ++k_) a2_[k_] = pA2_[4*k_ + quad]; \
    f32x4 cAa_[4], cBa_[4];                                     \
    _Pragma("unroll")                                           \
    for (int g_ = 0; g_ < 4; ++g_){                             \
      cAa_[g_] = MFMA16((a1)[0], B2i[g_][0], zacc);             \
      cBa_[g_] = MFMA16((a1)[2], B2i[g_][2], zacc);             \
    }                                                           \
    _Pragma("unroll")                                           \
    for (int g_ = 0; g_ < 4; ++g_){                             \
      cAa_[g_] = MFMA16((a1)[1], B2i[g_][1], cAa_[g_]);         \
      cBa_[g_] = MFMA16((a1)[3], B2i[g_][3], cBa_[g_]);         \
    }                                                           \
    _Pragma("unroll")                                           \
    for (int g_ = 0; g_ < 4; ++g_){                             \
      cAa_[g_] = MFMA16(a2_[0], B2h[g_][0], cAa_[g_]);          \
      cBa_[g_] = MFMA16(a2_[1], B2h[g_][1], cBa_[g_]);          \
    }                                                           \
    if (l < 16){                                                \
      float g4_[4];                                             \
      _Pragma("unroll")                                         \
      for (int g_ = 0; g_ < 4; ++g_)                            \
        g4_[g_] = cAa_[g_][0] + cBa_[g_][0] + bias2g[g_];       \
      c2 = sigmoid_f(g4_[1]) * c2 + sigmoid_f(g4_[0]) * tanh_f(g4_[2]); \
      float h_ = sigmoid_f(g4_[3]) * tanh_f(c2);                \
      if (store_out) out[b * EMB2 + cB] = h_;                   \
      else           H2[(s2) & 1][cB] = (_Float16)h_;           \
    }                                                           \
  }

  // ---- prologue: L1 step 0 (h1(-1) = zeros in slot 1) ----
  {
    f16x8 a1[4];
    LOAD_A1(1, a1);
    PHASE_A(a1, 0);
  }
  __syncthreads();

  // ---- main loop: superstep s = L1(s) || L2(s-1), one barrier ----
  #pragma unroll 1
  for (int s = 1; s < TB; ++s){
    f16x8 a1[4];
    LOAD_A1((s + 1) & 1, a1);      // h1(s-1), shared by both phases
    PHASE_A(a1, s);
    PHASE_B(a1, s - 1, false);
    __syncthreads();
  }

  // ---- epilogue: L2 step TB-1 -> output ----
  {
    f16x8 a1[4];
    LOAD_A1((TB - 1) & 1, a1);     // h1(TB-1)
    PHASE_B(a1, TB - 1, true);
  }

#undef LOAD_A1
#undef PHASE_A
#undef PHASE_B
}

extern "C" void kernel_launch(void* const* d_in, const int* in_sizes, int n_in,
                              void* d_out, int out_size, void* d_ws, size_t ws_size,
                              hipStream_t stream) {
  lstm2_kernel<<<dim3(128), dim3(256), 0, stream>>>(
      (const float*)d_in[0],   // x
      (const float*)d_in[1],   // w_ih1
      (const float*)d_in[2],   // w_hh1
      (const float*)d_in[3],   // b_ih1
      (const float*)d_in[4],   // b_hh1
      (const float*)d_in[5],   // w_ih2
      (const float*)d_in[6],   // w_hh2
      (const float*)d_in[7],   // b_ih2
      (const float*)d_in[8],   // b_hh2
      (float*)d_out);
}